// Round 1
// baseline (5829.802 us; speedup 1.0000x reference)
//
#include <hip/hip_runtime.h>
#include <stdint.h>

// TrianDecoder: 4-layer LSTM (B=32, T=64, H=1024) + vocab projection (V=32000) + softmax.
// Strategy: bf16 MFMA everywhere matmul-shaped, fp32 cell state / gates / accumulators.
// All MFMA operands pre-swizzled into fragment-native layout: frag load == global b128 at
// base + lane*16 (perfectly coalesced, no LDS staging in K-loops).

#define NL 4
#define BB 32
#define TT 64
#define HH 1024
#define VV 32000

typedef __attribute__((ext_vector_type(8))) short bf16x8;
typedef __attribute__((ext_vector_type(4))) float f32x4;

__device__ __forceinline__ unsigned short f2bf(float f) {
  union { float f; unsigned u; } v; v.f = f;
  unsigned u = v.u;
  u = u + 0x7fffu + ((u >> 16) & 1u);   // RNE
  return (unsigned short)(u >> 16);
}

// ---------------------------------------------------------------------------
// Generic weight swizzler: src fp32 row-major (K x N), dst bf16 fragment layout
// [nt][kq][lane][8] for mfma_f32_16x16x32_bf16 A/B operands:
//   lane holds elem [row/col = tilebase + (lane&15)][k = kq*32 + (lane>>4)*8 + j]
// mode 0 (plain):  col(nt,i) = nt*16 + i                     (Wfc)
// mode 1 (lstm):   col(nt,i) = (i>>2)*1024 + nt*4 + (i&3)    (gate-interleaved tiles)
// ---------------------------------------------------------------------------
__global__ void __launch_bounds__(256)
swizzle_w(const float* __restrict__ src, unsigned short* __restrict__ dst,
          int K, int N, int mode, long long src_lstride, long long dst_lstride) {
  int l = blockIdx.z;
  src += (long long)l * src_lstride;
  dst += (long long)l * dst_lstride;
  int k0  = blockIdx.x * 64;
  int ntb = blockIdx.y;            // group of 4 n-tiles (64 cols)
  __shared__ float lds[64][65];
  int tid = threadIdx.x;
  for (int it = 0; it < 16; ++it) {
    int idx = tid + it * 256;      // 0..4095
    int kk = idx >> 6;
    int cl = idx & 63;
    int col;
    if (mode == 1) col = ((cl >> 4) << 10) + ntb * 16 + (cl & 15);
    else           col = ntb * 64 + cl;
    lds[kk][cl] = src[(long long)(k0 + kk) * N + col];
  }
  __syncthreads();
  int kqn = K >> 5;
  for (int p = 0; p < 2; ++p) {
    int o = tid + p * 256;         // 0..511
    int lane = o & 63;
    int kql  = (o >> 6) & 1;
    int ntl  = o >> 7;             // 0..3
    int i = lane & 15;
    int kloc = kql * 32 + ((lane >> 4) << 3);
    int clocal;
    if (mode == 1) clocal = ((i >> 2) << 4) + ntl * 4 + (i & 3);
    else           clocal = ntl * 16 + i;
    unsigned short o8[8] __attribute__((aligned(16)));
    #pragma unroll
    for (int j = 0; j < 8; ++j) o8[j] = f2bf(lds[kloc + j][clocal]);
    int nt = ntb * 4 + ntl;
    int kq = (k0 >> 5) + kql;
    long long doff = ((((long long)nt * kqn) + kq) << 9) + (lane << 3);
    *reinterpret_cast<uint4*>(dst + doff) = *reinterpret_cast<const uint4*>(o8);
  }
}

// ---------------------------------------------------------------------------
// Embedding gather -> bf16 swizzled activation x_sw[t] ([rt][kq][lane][8], 32768 elems/t)
// ---------------------------------------------------------------------------
__global__ void __launch_bounds__(256)
embed_swz(const int* __restrict__ tok, const float* __restrict__ emb,
          unsigned short* __restrict__ xsw) {
  int gid = blockIdx.x * 256 + threadIdx.x;   // 64t * 2rt * 32kq * 64lane = 262144
  int lane = gid & 63;
  int kq = (gid >> 6) & 31;
  int rt = (gid >> 11) & 1;
  int t  = gid >> 12;
  int r = rt * 16 + (lane & 15);
  int k = kq * 32 + (((lane >> 4) & 3) << 3);
  int token = tok[r * TT + t];                // batch_target_in[b=r][t]
  const float* s = emb + (long long)token * HH + k;
  unsigned short o8[8] __attribute__((aligned(16)));
  #pragma unroll
  for (int j = 0; j < 8; ++j) o8[j] = f2bf(s[j]);
  long long off = (long long)t * 32768 + (((rt * 32 + kq) * 64 + lane) << 3);
  *reinterpret_cast<uint4*>(xsw + off) = *reinterpret_cast<const uint4*>(o8);
}

// ---------------------------------------------------------------------------
// Init h (bf16 swizzled, parity slot 1) and c (fp32 plain) from states
// ---------------------------------------------------------------------------
__global__ void __launch_bounds__(256)
init_hc(const float* __restrict__ states, unsigned short* __restrict__ hsw,
        float* __restrict__ cbuf) {
  int gid = blockIdx.x * 256 + threadIdx.x;   // 4l * 2rt * 32kq * 64lane = 16384
  int lane = gid & 63;
  int kq = (gid >> 6) & 31;
  int rt = (gid >> 11) & 1;
  int l  = gid >> 12;
  int r = rt * 16 + (lane & 15);
  int k = kq * 32 + (((lane >> 4) & 3) << 3);
  const float* hs = states + (long long)(2 * l) * (BB * HH) + r * HH + k;
  unsigned short o8[8] __attribute__((aligned(16)));
  #pragma unroll
  for (int j = 0; j < 8; ++j) o8[j] = f2bf(hs[j]);
  long long off = (long long)(l * 2 + 1) * 32768 + (((rt * 32 + kq) * 64 + lane) << 3);
  *reinterpret_cast<uint4*>(hsw + off) = *reinterpret_cast<const uint4*>(o8);
  const float* cs = states + (long long)(2 * l + 1) * (BB * HH) + r * HH + k;
  float* cd = cbuf + (long long)l * (BB * HH) + r * HH + k;
  #pragma unroll
  for (int j = 0; j < 8; ++j) cd[j] = cs[j];
}

// ---------------------------------------------------------------------------
// Persistent LSTM kernel: 256 blocks (1/CU) x 256 threads, custom grid barrier.
// Block bid owns h-cols {bid*4 .. bid*4+3} -> 16 z-cols {q*1024 + bid*4 + jj}.
// z^T formulation: D[c][r] = (W^T)(c,k) x inp(r,k); both frags are contiguous b128.
// 4 waves split K: waves 0/1 = x-side (Wx) halves, waves 2/3 = h-side (Wh) halves.
// ---------------------------------------------------------------------------
__global__ void __launch_bounds__(256)
lstm_kernel(const unsigned short* __restrict__ Wsw,  // [l*2+mat][256ct][32kq][64][8]
            const float* __restrict__ bias,          // (4, 4096)
            const unsigned short* __restrict__ xsw,  // [64t][32768]
            unsigned short* hsw,                     // [l*2+parity][32768]
            float* cbuf,                             // [4][32x1024]
            unsigned short* topsw,                   // [64t][32768]
            unsigned* ctr) {
  const int tid  = threadIdx.x;
  const int wave = tid >> 6;
  const int lane = tid & 63;
  const int bid  = blockIdx.x;            // = ct, 0..255
  const int mat  = wave >> 1;             // 0: Wx*inp, 1: Wh*hprev
  const int kqb  = (wave & 1) * 16;       // kq range [kqb, kqb+16)

  __shared__ float zsh[4][16][33];        // [wave][c-local][r]

  for (int t = 0; t < TT; ++t) {
    for (int l = 0; l < NL; ++l) {
      const unsigned short* wbase =
          Wsw + ((((l * 2 + mat) * 256 + bid) * 32 + kqb) << 9) + (lane << 3);
      const unsigned short* ibase;
      if (mat == 0)
        ibase = (l == 0) ? (xsw + (long long)t * 32768)
                         : (hsw + (long long)((l - 1) * 2 + (t & 1)) * 32768);
      else
        ibase = hsw + (long long)(l * 2 + ((t + 1) & 1)) * 32768;
      ibase += (kqb << 9) + (lane << 3);

      f32x4 acc0 = {0.f, 0.f, 0.f, 0.f};
      f32x4 acc1 = {0.f, 0.f, 0.f, 0.f};
      #pragma unroll 4
      for (int s = 0; s < 16; ++s) {
        bf16x8 a  = *reinterpret_cast<const bf16x8*>(wbase + (s << 9));
        bf16x8 b0 = *reinterpret_cast<const bf16x8*>(ibase + (s << 9));
        bf16x8 b1 = *reinterpret_cast<const bf16x8*>(ibase + 16384 + (s << 9));
        acc0 = __builtin_amdgcn_mfma_f32_16x16x32_bf16(a, b0, acc0, 0, 0, 0);
        acc1 = __builtin_amdgcn_mfma_f32_16x16x32_bf16(a, b1, acc1, 0, 0, 0);
      }
      // park partial z^T in LDS: D row m=(lane>>4)*4+reg (c-local), col n=lane&15 (r)
      {
        int i4 = (lane >> 4) << 2;
        int rl = lane & 15;
        #pragma unroll
        for (int reg = 0; reg < 4; ++reg) {
          zsh[wave][i4 + reg][rl]      = acc0[reg];
          zsh[wave][i4 + reg][16 + rl] = acc1[reg];
        }
      }
      __syncthreads();
      // gates: 128 threads, thread = (r, jj)
      if (tid < 128) {
        int r  = tid & 31;
        int jj = tid >> 5;
        int jcol = bid * 4 + jj;
        float zg[4];
        #pragma unroll
        for (int q = 0; q < 4; ++q) {
          int i = q * 4 + jj;
          float z = zsh[0][i][r] + zsh[1][i][r] + zsh[2][i][r] + zsh[3][i][r];
          zg[q] = z + bias[(l << 12) + (q << 10) + jcol];
        }
        float si = 1.f / (1.f + __expf(-zg[0]));
        float sf = 1.f / (1.f + __expf(-zg[1]));
        float so = 1.f / (1.f + __expf(-zg[3]));
        float e2 = __expf(-2.f * fabsf(zg[2]));
        float tg = (1.f - e2) / (1.f + e2);
        tg = zg[2] < 0.f ? -tg : tg;
        float* cp = cbuf + (long long)l * (BB * HH) + r * HH + jcol;
        float cnew = sf * (*cp) + si * tg;
        *cp = cnew;
        float e2c = __expf(-2.f * fabsf(cnew));
        float th = (1.f - e2c) / (1.f + e2c);
        th = cnew < 0.f ? -th : th;
        unsigned short hb = f2bf(so * th);
        int rt = r >> 4, kq = jcol >> 5;
        int ln = (r & 15) | (((jcol >> 3) & 3) << 4);
        int hoff = (((rt << 5) | kq) << 9) | (ln << 3) | (jcol & 7);
        hsw[(long long)(l * 2 + (t & 1)) * 32768 + hoff] = hb;
        if (l == 3) topsw[(long long)t * 32768 + hoff] = hb;
      }
      // grid barrier (agent-scope: release flushes L2, acquire invalidates)
      __syncthreads();
      if (tid == 0) {
        __hip_atomic_fetch_add(ctr, 1u, __ATOMIC_RELEASE, __HIP_MEMORY_SCOPE_AGENT);
        unsigned tgt = 256u * (unsigned)(t * NL + l + 1);
        while (__hip_atomic_load(ctr, __ATOMIC_RELAXED, __HIP_MEMORY_SCOPE_AGENT) < tgt)
          __builtin_amdgcn_s_sleep(2);
        (void)__hip_atomic_load(ctr, __ATOMIC_ACQUIRE, __HIP_MEMORY_SCOPE_AGENT);
      }
      __syncthreads();
    }
  }
}

// ---------------------------------------------------------------------------
// Projection: logits(2048 x 32000) = tops(2048x1024) @ Wfc(1024x32000) + bfc
// Block = M128 x N256 (4 waves, wave = 8mt x 4nt). Fragment-direct global loads.
// Writes logits into d_out at out[b][t][v] (m = t*32 + b).
// ---------------------------------------------------------------------------
__global__ void __launch_bounds__(256)
final_gemm(const unsigned short* __restrict__ topsw,  // [128mt][32kq][64][8]
           const unsigned short* __restrict__ wfcsw,  // [2000nt][32kq][64][8]
           const float* __restrict__ bfc,
           float* __restrict__ out) {
  int tid = threadIdx.x, wave = tid >> 6, lane = tid & 63;
  int mtb = blockIdx.y * 8;
  int ntb = blockIdx.x * 16 + wave * 4;
  f32x4 acc[8][4];
  #pragma unroll
  for (int i = 0; i < 8; ++i)
    #pragma unroll
    for (int n = 0; n < 4; ++n) acc[i][n] = (f32x4){0.f, 0.f, 0.f, 0.f};
  const unsigned short* abase = topsw + (((long long)mtb * 32) << 9) + (lane << 3);
  const unsigned short* bbase = wfcsw + (((long long)ntb * 32) << 9) + (lane << 3);
  for (int kq = 0; kq < 32; ++kq) {
    bf16x8 bf[4];
    #pragma unroll
    for (int n = 0; n < 4; ++n)
      bf[n] = *reinterpret_cast<const bf16x8*>(bbase + (((n * 32 + kq)) << 9));
    #pragma unroll
    for (int i = 0; i < 8; ++i) {
      bf16x8 af = *reinterpret_cast<const bf16x8*>(abase + (((i * 32 + kq)) << 9));
      #pragma unroll
      for (int n = 0; n < 4; ++n)
        acc[i][n] = __builtin_amdgcn_mfma_f32_16x16x32_bf16(af, bf[n], acc[i][n], 0, 0, 0);
    }
  }
  int i4 = (lane >> 4) << 2;
  int nl = lane & 15;
  #pragma unroll
  for (int i = 0; i < 8; ++i) {
    int mt = mtb + i;
    #pragma unroll
    for (int n = 0; n < 4; ++n) {
      int v = (ntb + n) * 16 + nl;
      float bv = bfc[v];
      #pragma unroll
      for (int reg = 0; reg < 4; ++reg) {
        int m = mt * 16 + i4 + reg;        // m = t*32 + b
        int b = m & 31, t = m >> 5;
        out[((long long)b * TT + t) * VV + v] = acc[i][n][reg] + bv;
      }
    }
  }
}

// ---------------------------------------------------------------------------
// In-place row softmax over V=32000 (one block per (b,t) row)
// ---------------------------------------------------------------------------
__global__ void __launch_bounds__(256)
softmax_k(float* __restrict__ out) {
  float* p = out + (long long)blockIdx.x * VV;
  int tid = threadIdx.x;
  __shared__ float red[24];
  float m = -1e30f;
  for (int i = tid; i < VV; i += 256) m = fmaxf(m, p[i]);
  #pragma unroll
  for (int o = 32; o > 0; o >>= 1) m = fmaxf(m, __shfl_down(m, o, 64));
  if ((tid & 63) == 0) red[tid >> 6] = m;
  __syncthreads();
  if (tid == 0) red[8] = fmaxf(fmaxf(red[0], red[1]), fmaxf(red[2], red[3]));
  __syncthreads();
  float mm = red[8];
  float s = 0.f;
  for (int i = tid; i < VV; i += 256) s += __expf(p[i] - mm);
  #pragma unroll
  for (int o = 32; o > 0; o >>= 1) s += __shfl_down(s, o, 64);
  if ((tid & 63) == 0) red[16 + (tid >> 6)] = s;
  __syncthreads();
  if (tid == 0) red[9] = 1.f / (red[16] + red[17] + red[18] + red[19]);
  __syncthreads();
  float inv = red[9];
  for (int i = tid; i < VV; i += 256) p[i] = __expf(p[i] - mm) * inv;
}

// ---------------------------------------------------------------------------
extern "C" void kernel_launch(void* const* d_in, const int* in_sizes, int n_in,
                              void* d_out, int out_size, void* d_ws, size_t ws_size,
                              hipStream_t stream) {
  const int*   tok    = (const int*)  d_in[0];
  const float* states = (const float*)d_in[1];
  const float* emb    = (const float*)d_in[2];
  const float* Wx     = (const float*)d_in[3];
  const float* Wh     = (const float*)d_in[4];
  const float* bias   = (const float*)d_in[5];
  const float* Wfc    = (const float*)d_in[6];
  const float* bfc    = (const float*)d_in[7];
  float* out = (float*)d_out;

  char* ws = (char*)d_ws;
  unsigned* ctr = (unsigned*)ws;
  size_t off = 256;
  unsigned short* Wsw   = (unsigned short*)(ws + off); off += (size_t)8 * 1024 * 4096 * 2;   // 67.1 MB
  unsigned short* Wfcsw = (unsigned short*)(ws + off); off += (size_t)VV * HH * 2;           // 65.5 MB
  unsigned short* xsw   = (unsigned short*)(ws + off); off += (size_t)TT * 32768 * 2;        // 4.2 MB
  unsigned short* topsw = (unsigned short*)(ws + off); off += (size_t)TT * 32768 * 2;        // 4.2 MB
  unsigned short* hsw   = (unsigned short*)(ws + off); off += (size_t)8 * 32768 * 2;         // 0.5 MB
  float*          cbuf  = (float*)(ws + off);          off += (size_t)NL * BB * HH * 4;      // 0.5 MB

  hipMemsetAsync(ctr, 0, 256, stream);

  // Wx -> even lmat slots, Wh -> odd lmat slots (gate-interleaved col tiles)
  swizzle_w<<<dim3(16, 64, 4), 256, 0, stream>>>(
      Wx, Wsw, HH, 4 * HH, 1, (long long)HH * 4 * HH, (long long)2 * HH * 4 * HH);
  swizzle_w<<<dim3(16, 64, 4), 256, 0, stream>>>(
      Wh, Wsw + (size_t)HH * 4 * HH, HH, 4 * HH, 1,
      (long long)HH * 4 * HH, (long long)2 * HH * 4 * HH);
  // Wfc plain 16-col tiles
  swizzle_w<<<dim3(16, 500, 1), 256, 0, stream>>>(Wfc, Wfcsw, HH, VV, 0, 0, 0);

  embed_swz<<<1024, 256, 0, stream>>>(tok, emb, xsw);
  init_hc<<<64, 256, 0, stream>>>(states, hsw, cbuf);

  lstm_kernel<<<256, 256, 0, stream>>>(Wsw, bias, xsw, hsw, cbuf, topsw, ctr);

  final_gemm<<<dim3(125, 16), 256, 0, stream>>>(topsw, Wfcsw, bfc, out);
  softmax_k<<<BB * TT, 256, 0, stream>>>(out);
}